// Round 10
// baseline (67.126 us; speedup 1.0000x reference)
//
#include <hip/hip_runtime.h>
#include <hip/hip_bf16.h>
#include <stdint.h>

// Problem constants: N=8192 tokens, D=1024, U=512, E=8, B=8 bases.
#define NTOK 8192
#define DDIM 1024
#define UDIM 512
#define NEXP 8
#define MT_MAX 136   // max padded 64-row M-tiles: 8192/64 + 7 partials + slack

typedef __attribute__((ext_vector_type(8))) short bf16x8;
typedef __attribute__((ext_vector_type(4))) float f32x4;

// ---- helpers ---------------------------------------------------------------

__device__ __forceinline__ unsigned short f2bf(float f) {
  unsigned int u = __float_as_uint(f);
  u += 0x7FFFu + ((u >> 16) & 1u);
  return (unsigned short)(u >> 16);
}

__device__ __forceinline__ void gload16(const void* g, void* lds) {
  // async global->LDS, 16B/lane; LDS dest = wave-uniform base + lane*16 (HW rule);
  // global source address is per-lane (gather allowed).
  __builtin_amdgcn_global_load_lds(
      (__attribute__((address_space(1))) void*)(uintptr_t)g,
      (__attribute__((address_space(3))) void*)(uint32_t)(uintptr_t)lds,
      16, 0, 0);
}

// ---- fused prep+pack: block-range split ------------------------------------
// blocks [0,2048): gating (f32 logits, argmax, NO atomics) + x -> bf16
// blocks [2048,4096): weight packing [E][R][C] f32 -> [kt][C][32] bf16 panels

__global__ __launch_bounds__(256) void k_prep_pack(
    const float* __restrict__ x, const float* __restrict__ Wg,
    const float* __restrict__ bg, const float* __restrict__ W1,
    const float* __restrict__ proj, unsigned short* __restrict__ xbf,
    int* __restrict__ eidx, unsigned short* __restrict__ W1p,
    unsigned short* __restrict__ projp) {
  __shared__ __align__(16) char smem[8 * 1040 * 4];  // union: WgT | pack tile
  const int t = threadIdx.x;

  if (blockIdx.x < 2048) {
    // ---- gating + bf16 conversion (4 token-waves / block) ----
    float (*WgT)[1040] = (float(*)[1040])smem;
#pragma unroll
    for (int r = 0; r < 32; ++r)
      WgT[t & 7][r * 32 + (t >> 3)] = Wg[r * 256 + t];
    __syncthreads();

    const int lane = t & 63;
    const int n = (blockIdx.x << 2) + (t >> 6);
    const float* xr = x + (size_t)n * DDIM;
    unsigned short* xo = xbf + (size_t)n * DDIM;
    float acc[8] = {0.f, 0.f, 0.f, 0.f, 0.f, 0.f, 0.f, 0.f};
#pragma unroll
    for (int c = 0; c < 4; ++c) {
      const int d = c * 256 + lane * 4;
      const float4 xv = *(const float4*)(xr + d);
      ushort4 o;
      o.x = f2bf(xv.x); o.y = f2bf(xv.y); o.z = f2bf(xv.z); o.w = f2bf(xv.w);
      *(ushort4*)(xo + d) = o;
#pragma unroll
      for (int e = 0; e < 8; ++e) {
        const float4 wv = *(const float4*)(&WgT[e][d]);
        acc[e] = fmaf(xv.x, wv.x, acc[e]);
        acc[e] = fmaf(xv.y, wv.y, acc[e]);
        acc[e] = fmaf(xv.z, wv.z, acc[e]);
        acc[e] = fmaf(xv.w, wv.w, acc[e]);
      }
    }
#pragma unroll
    for (int e = 0; e < 8; ++e) {
#pragma unroll
      for (int o = 32; o > 0; o >>= 1) acc[e] += __shfl_xor(acc[e], o, 64);
    }
    if (lane == 0) {
      int best = 0;
      float bv = acc[0] + bg[0];
#pragma unroll
      for (int e2 = 1; e2 < 8; ++e2) {
        const float v = acc[e2] + bg[e2];
        if (v > bv) { bv = v; best = e2; }  // strict > = np.argmax first-index ties
      }
      eidx[n] = best;
    }
  } else {
    // ---- weight packing ----
    float (*tile)[65] = (float(*)[65])smem;
    const int id = blockIdx.x - 2048;
    const int c0 = (id & 7) << 6;
    const int r0 = ((id >> 3) & 15) << 6;
    const int z = id >> 7;  // 0..15
    const int R = (z < 8) ? DDIM : UDIM;
    if (r0 >= R) return;
    const float* src = (z < 8) ? (W1 + (size_t)z * DDIM * UDIM)
                               : (proj + (size_t)(z - 8) * UDIM * UDIM);
    unsigned short* dst = (z < 8) ? (W1p + (size_t)z * DDIM * UDIM)
                                  : (projp + (size_t)(z - 8) * UDIM * UDIM);
#pragma unroll
    for (int i = 0; i < 4; ++i) {
      const int ri = (t >> 4) + i * 16;
      const int ci = (t & 15) * 4;
      const float4 v = *(const float4*)(src + (size_t)(r0 + ri) * UDIM + c0 + ci);
      tile[ri][ci] = v.x; tile[ri][ci + 1] = v.y; tile[ri][ci + 2] = v.z; tile[ri][ci + 3] = v.w;
    }
    __syncthreads();
    const int cc = t >> 2, ch = t & 3;
#pragma unroll
    for (int j = 0; j < 2; ++j) {
      const int kt = (r0 >> 5) + j;
      union { bf16x8 v; unsigned short u[8]; } pk;
#pragma unroll
      for (int q = 0; q < 8; ++q) pk.u[q] = f2bf(tile[j * 32 + ch * 8 + q][cc]);
      *(bf16x8*)(dst + ((size_t)kt * UDIM + c0 + cc) * 32 + ch * 8) = pk.v;
    }
  }
}

// ---- sort: wave-shuffle scans, 3 barriers, ZERO atomics --------------------
// 1 block x 1024 threads (16 waves); thread t owns tokens [t*8, t*8+8).

__global__ __launch_bounds__(1024) void k_sort(const int* __restrict__ eidx,
                                               int* __restrict__ perm_p,
                                               int* __restrict__ tile_expert,
                                               int* __restrict__ tile_rowlim) {
  __shared__ int wavetot[8][16];  // per-bin per-wave totals -> exclusive prefix
  __shared__ int tot[8];
  __shared__ int tbase[9];
  const int t = threadIdx.x;
  const int lane = t & 63, wid = t >> 6;

  int my[8], c[8] = {0, 0, 0, 0, 0, 0, 0, 0};
#pragma unroll
  for (int i = 0; i < 8; ++i) {
    my[i] = eidx[t * 8 + i];
#pragma unroll
    for (int b = 0; b < 8; ++b) c[b] += (my[i] == b);
  }

  // inclusive scan within each wave, per bin
  int inc[8];
#pragma unroll
  for (int b = 0; b < 8; ++b) {
    int v = c[b];
#pragma unroll
    for (int o = 1; o < 64; o <<= 1) {
      const int u = __shfl_up(v, o, 64);
      if (lane >= o) v += u;
    }
    inc[b] = v;
  }
  if (lane == 63) {
#pragma unroll
    for (int b = 0; b < 8; ++b) wavetot[b][wid] = inc[b];
  }
  __syncthreads();

  if (t < 8) {  // exclusive scan of 16 wave totals for bin t
    int run = 0;
#pragma unroll
    for (int w2 = 0; w2 < 16; ++w2) {
      const int u = wavetot[t][w2];
      wavetot[t][w2] = run;
      run += u;
    }
    tot[t] = run;
  }
  __syncthreads();
  if (t == 0) {
    int run = 0;
    for (int e = 0; e < 8; ++e) { tbase[e] = run; run += (tot[e] + 63) >> 6; }
    tbase[8] = run;
  }
  __syncthreads();

  // stable scatter: padded segment base + wave prefix + in-wave exclusive prefix
  int base[8];
#pragma unroll
  for (int b = 0; b < 8; ++b)
    base[b] = (tbase[b] << 6) + wavetot[b][wid] + inc[b] - c[b];
#pragma unroll
  for (int b = 0; b < 8; ++b) {
    int p = base[b];
#pragma unroll
    for (int i = 0; i < 8; ++i)
      if (my[i] == b) perm_p[p++] = t * 8 + i;
  }

  if (t < MT_MAX) {
    int e = -1, rl = 0;
#pragma unroll
    for (int q = 0; q < 8; ++q) {
      if (t >= tbase[q] && t < tbase[q + 1]) {
        e = q;
        const int r = tot[q] - (t - tbase[q]) * 64;
        rl = r < 64 ? r : 64;
      }
    }
    tile_expert[t] = e;
    tile_rowlim[t] = rl;
  }
}

// ---- GEMM1: H = swish(xbf[tok] @ W1[e] + b1[e]) -> Hp panels bf16 ----------
// 64x64 tile, BK=32, 4 waves, 24KB LDS TRIPLE-buffer, counted vmcnt(2):
// prefetch distance 2 so staging loads stay in flight across the barrier (T4).

__global__ __launch_bounds__(256) void k_gemm1(
    const unsigned short* __restrict__ xbf, const unsigned short* __restrict__ W1p,
    const float* __restrict__ b1, const int* __restrict__ perm_p,
    const int* __restrict__ tile_expert, const int* __restrict__ tile_rowlim,
    unsigned short* __restrict__ Hp) {
  __shared__ __align__(16) short Ab[3][64 * 32];
  __shared__ __align__(16) short Bb[3][64 * 32];
  __shared__ int rows_s[64];

  const int orig = blockIdx.x;                      // 0..1087, 8 XCD chunks
  const int wg = (orig & 7) * MT_MAX + (orig >> 3);
  const int Mt = wg >> 3, Nt = wg & 7;
  const int e = tile_expert[Mt];
  if (e < 0) return;
  const int rowlim = tile_rowlim[Mt];

  const int t = threadIdx.x;
  const int w = t >> 6, wr = w >> 1, wc = w & 1;
  const int lane = t & 63, ln15 = lane & 15, g = lane >> 4;

  if (t < 64) rows_s[t] = perm_p[Mt * 64 + (t < rowlim ? t : 0)];
  __syncthreads();

  const int srow = t >> 2;                       // staged row/col 0..63
  const int sh = (t & 3) ^ ((srow >> 1) & 3);    // pre-swizzled source chunk
  const unsigned short* arow = xbf + (size_t)rows_s[srow] * DDIM + sh * 8;
  const unsigned short* Bpan = W1p + ((size_t)e * 32 * UDIM + Nt * 64) * 32;

  auto stage = [&](int kt, int buf) {
    gload16(arow + kt * 32, (char*)Ab[buf] + (t & ~63) * 16);
    gload16(Bpan + (size_t)kt * UDIM * 32 + srow * 32 + sh * 8,
            (char*)Bb[buf] + (t & ~63) * 16);
  };

  f32x4 acc[2][2];
  const f32x4 z4 = {0.f, 0.f, 0.f, 0.f};
  acc[0][0] = z4; acc[0][1] = z4; acc[1][0] = z4; acc[1][1] = z4;

  stage(0, 0);
  stage(1, 1);
  const int NK = 32;
  int cur = 0;
  for (int kt = 0; kt < NK; ++kt) {
    // wait for stage(kt) only; stage(kt+1)'s 2 loads stay in flight (T4)
    __builtin_amdgcn_sched_barrier(0);
    if (kt + 1 < NK) asm volatile("s_waitcnt vmcnt(2)" ::: "memory");
    else             asm volatile("s_waitcnt vmcnt(0)" ::: "memory");
    __builtin_amdgcn_s_barrier();
    __builtin_amdgcn_sched_barrier(0);

    bf16x8 af[2], bf_[2];
#pragma unroll
    for (int mt = 0; mt < 2; ++mt) {
      const int r = wr * 32 + mt * 16 + ln15;
      af[mt] = *(const bf16x8*)((const char*)Ab[cur] + r * 64 + (g ^ ((r >> 1) & 3)) * 16);
    }
#pragma unroll
    for (int nt = 0; nt < 2; ++nt) {
      const int c2 = wc * 32 + nt * 16 + ln15;
      bf_[nt] = *(const bf16x8*)((const char*)Bb[cur] + c2 * 64 + (g ^ ((c2 >> 1) & 3)) * 16);
    }
#pragma unroll
    for (int mt = 0; mt < 2; ++mt)
#pragma unroll
      for (int nt = 0; nt < 2; ++nt)
        acc[mt][nt] = __builtin_amdgcn_mfma_f32_16x16x32_bf16(af[mt], bf_[nt], acc[mt][nt], 0, 0, 0);

    if (kt + 2 < NK) stage(kt + 2, (cur + 2) % 3);  // overwrites b[kt-1]: safe, all
    cur = (cur + 1) % 3;                            // waves passed this step's barrier
  }

  // epilogue: +b1, swish (rcp-based), store bf16 into Hp panel-major
  float bv[2];
#pragma unroll
  for (int nt = 0; nt < 2; ++nt)
    bv[nt] = b1[e * UDIM + Nt * 64 + wc * 32 + nt * 16 + ln15];
#pragma unroll
  for (int mt = 0; mt < 2; ++mt) {
#pragma unroll
    for (int nt = 0; nt < 2; ++nt) {
      const int colg = Nt * 64 + wc * 32 + nt * 16 + ln15;
      unsigned short* hp = Hp + ((size_t)(Mt * 16 + (colg >> 5)) * 64) * 32 + (colg & 31);
#pragma unroll
      for (int r = 0; r < 4; ++r) {
        const int row = wr * 32 + mt * 16 + g * 4 + r;
        const float a = acc[mt][nt][r] + bv[nt];
        hp[(size_t)row * 32] = f2bf(a * __builtin_amdgcn_rcpf(1.f + __expf(-a)));
      }
    }
  }
}

// ---- GEMM2: Z = H @ proj[e]; fused sigmoid->RBF->ctrl->scale->scatter ------
// Same triple-buffer counted-vmcnt schedule; same XCD-chunked 1D grid.

__global__ __launch_bounds__(256) void k_gemm2(
    const unsigned short* __restrict__ Hp, const unsigned short* __restrict__ projp,
    const float* __restrict__ ctrl, const float* __restrict__ scaling,
    const int* __restrict__ perm_p, const int* __restrict__ tile_expert,
    const int* __restrict__ tile_rowlim, float* __restrict__ out) {
  __shared__ __align__(16) short Ab[3][64 * 32];
  __shared__ __align__(16) short Bb[3][64 * 32];
  __shared__ int tok_s[64];

  const int orig = blockIdx.x;
  const int wg = (orig & 7) * MT_MAX + (orig >> 3);
  const int Mt = wg >> 3, Nt = wg & 7;
  const int e = tile_expert[Mt];
  if (e < 0) return;
  const int rowlim = tile_rowlim[Mt];

  const int t = threadIdx.x;
  const int w = t >> 6, wr = w >> 1, wc = w & 1;
  const int lane = t & 63, ln15 = lane & 15, g = lane >> 4;

  if (t < 64) tok_s[t] = perm_p[Mt * 64 + (t < rowlim ? t : 0)];
  __syncthreads();

  const int srow = t >> 2;
  const int sh = (t & 3) ^ ((srow >> 1) & 3);
  const unsigned short* Apan = Hp + ((size_t)Mt * 16 * 64) * 32;
  const unsigned short* Bpan = projp + ((size_t)e * 16 * UDIM + Nt * 64) * 32;

  auto stage = [&](int kt, int buf) {
    gload16(Apan + (size_t)kt * 64 * 32 + srow * 32 + sh * 8,
            (char*)Ab[buf] + (t & ~63) * 16);
    gload16(Bpan + (size_t)kt * UDIM * 32 + srow * 32 + sh * 8,
            (char*)Bb[buf] + (t & ~63) * 16);
  };

  f32x4 acc[2][2];
  const f32x4 z4 = {0.f, 0.f, 0.f, 0.f};
  acc[0][0] = z4; acc[0][1] = z4; acc[1][0] = z4; acc[1][1] = z4;

  stage(0, 0);
  stage(1, 1);
  const int NK = 16;
  int cur = 0;
  for (int kt = 0; kt < NK; ++kt) {
    __builtin_amdgcn_sched_barrier(0);
    if (kt + 1 < NK) asm volatile("s_waitcnt vmcnt(2)" ::: "memory");
    else             asm volatile("s_waitcnt vmcnt(0)" ::: "memory");
    __builtin_amdgcn_s_barrier();
    __builtin_amdgcn_sched_barrier(0);

    bf16x8 af[2], bf_[2];
#pragma unroll
    for (int mt = 0; mt < 2; ++mt) {
      const int r = wr * 32 + mt * 16 + ln15;
      af[mt] = *(const bf16x8*)((const char*)Ab[cur] + r * 64 + (g ^ ((r >> 1) & 3)) * 16);
    }
#pragma unroll
    for (int nt = 0; nt < 2; ++nt) {
      const int c2 = wc * 32 + nt * 16 + ln15;
      bf_[nt] = *(const bf16x8*)((const char*)Bb[cur] + c2 * 64 + (g ^ ((c2 >> 1) & 3)) * 16);
    }
#pragma unroll
    for (int mt = 0; mt < 2; ++mt)
#pragma unroll
      for (int nt = 0; nt < 2; ++nt)
        acc[mt][nt] = __builtin_amdgcn_mfma_f32_16x16x32_bf16(af[mt], bf_[nt], acc[mt][nt], 0, 0, 0);

    if (kt + 2 < NK) stage(kt + 2, (cur + 2) % 3);
    cur = (cur + 1) % 3;
  }

  // epilogue: sigmoid -> RBF via geometric recurrence -> ctrl dot -> scale.
  const float M = 0.27086949f;  // exp(-64/49)
  float cv[2][8], sc[2];
#pragma unroll
  for (int nt = 0; nt < 2; ++nt) {
    const int colg = Nt * 64 + wc * 32 + nt * 16 + ln15;
    sc[nt] = scaling[e * UDIM + colg];
#pragma unroll
    for (int b = 0; b < 8; ++b) cv[nt][b] = ctrl[((size_t)e * 8 + b) * UDIM + colg];
  }
#pragma unroll
  for (int mt = 0; mt < 2; ++mt) {
#pragma unroll
    for (int r = 0; r < 4; ++r) {
      const int row = wr * 32 + mt * 16 + g * 4 + r;
      if (row < rowlim) {
        const int tok = tok_s[row];
#pragma unroll
        for (int nt = 0; nt < 2; ++nt) {
          const int colg = Nt * 64 + wc * 32 + nt * 16 + ln15;
          const float z = acc[mt][nt][r];
          const float xn = __builtin_amdgcn_rcpf(1.f + __expf(-z));
          float q = __expf(-32.f * xn * xn);                     // basis_0
          float rr = __expf(xn * (64.f / 7.f) - (32.f / 49.f));  // step ratio
          float s = 0.f, dc = 0.f;
#pragma unroll
          for (int b = 0; b < 8; ++b) {
            s += q;
            dc = fmaf(q, cv[nt][b], dc);
            q *= rr;
            rr *= M;
          }
          out[(size_t)tok * UDIM + colg] = dc * __builtin_amdgcn_rcpf(s + 1e-6f) * sc[nt];
        }
      }
    }
  }
}

// ---- host launch -----------------------------------------------------------

extern "C" void kernel_launch(void* const* d_in, const int* in_sizes, int n_in,
                              void* d_out, int out_size, void* d_ws, size_t ws_size,
                              hipStream_t stream) {
  const float* x       = (const float*)d_in[0];
  const float* W1      = (const float*)d_in[1];
  const float* b1      = (const float*)d_in[2];
  const float* proj    = (const float*)d_in[3];
  const float* ctrl    = (const float*)d_in[4];
  const float* scaling = (const float*)d_in[5];
  const float* Wg      = (const float*)d_in[6];
  const float* bg      = (const float*)d_in[7];
  float* out = (float*)d_out;
  char* ws = (char*)d_ws;

  // workspace layout (~37.1 MB)
  int* eidx        = (int*)(ws + 0);                 // 32KB
  int* perm_p      = (int*)(ws + 32768);             // 8704*4
  int* tile_expert = (int*)(ws + 69632 + 64);        // 544B
  int* tile_rowlim = (int*)(ws + 69632 + 640);       // 544B
  unsigned short* W1p   = (unsigned short*)(ws + 131072);                        // 8MB
  unsigned short* projp = (unsigned short*)(ws + 131072 + 8388608);              // 4MB
  unsigned short* Hp    = (unsigned short*)(ws + 131072 + 8388608 + 4194304);    // 8.9MB
  unsigned short* xbf   = (unsigned short*)(ws + 131072 + 8388608 + 4194304 + 9175040);  // 16MB

  k_prep_pack<<<4096, 256, 0, stream>>>(x, Wg, bg, W1, proj, xbf, eidx, W1p, projp);
  k_sort<<<1, 1024, 0, stream>>>(eidx, perm_p, tile_expert, tile_rowlim);
  k_gemm1<<<MT_MAX * 8, 256, 0, stream>>>(xbf, W1p, b1, perm_p,
                                          tile_expert, tile_rowlim, Hp);
  k_gemm2<<<MT_MAX * 8, 256, 0, stream>>>(Hp, projp, ctrl, scaling, perm_p,
                                          tile_expert, tile_rowlim, out);
}